// Round 9
// baseline (899.131 us; speedup 1.0000x reference)
//
#include <hip/hip_runtime.h>
#include <stdint.h>

#define DMODEL 2048
#define NH 16
#define HD 128
#define BATCH 4
#define SEQ 2048
#define MTOT (BATCH * SEQ)  // 8192
#define LOG2E 1.44269504088896340736f

typedef __bf16 bf16x8 __attribute__((ext_vector_type(8)));
typedef float floatx4 __attribute__((ext_vector_type(4)));

__device__ __forceinline__ uint16_t f2b(float f) {
    union { float f; uint32_t i; } v; v.f = f;
    uint32_t r = v.i + 0x7fffu + ((v.i >> 16) & 1u);
    return (uint16_t)(r >> 16);
}

// pack two f32 -> one u32 of 2 bf16 (RNE). No builtin on gfx950 (m240).
__device__ __forceinline__ uint32_t cvtpk(float lo, float hi) {
    uint32_t r;
    asm("v_cvt_pk_bf16_f32 %0, %1, %2" : "=v"(r) : "v"(lo), "v"(hi));
    return r;
}

// async global->LDS, 16B per lane, wave-uniform LDS base + lane*16
#define GLD16(gp, lp)                                                          \
    __builtin_amdgcn_global_load_lds(                                          \
        (__attribute__((address_space(1))) unsigned int*)(gp),                 \
        (__attribute__((address_space(3))) unsigned int*)(lp), 16, 0, 0)

#define WAITVMC(N) asm volatile("s_waitcnt vmcnt(" #N ")" ::: "memory")
#define WAITLGKM0                                                              \
    do {                                                                       \
        asm volatile("s_waitcnt lgkmcnt(0)" ::: "memory");                     \
        __builtin_amdgcn_sched_barrier(0);                                     \
    } while (0)

// ---------------------------------------------------------------------------
// fp32 -> bf16 elementwise convert. n multiple of 8. grid n/2048.
// ---------------------------------------------------------------------------
__global__ __launch_bounds__(256) void cvt_bf16(const float* __restrict__ in,
                                                uint16_t* __restrict__ out, int n) {
    const int i = (blockIdx.x * 256 + threadIdx.x) * 8;
    if (i >= n) return;
    const float4 a = *(const float4*)(in + i);
    const float4 b = *(const float4*)(in + i + 4);
    uint16_t v[8] __attribute__((aligned(16))) = {
        f2b(a.x), f2b(a.y), f2b(a.z), f2b(a.w),
        f2b(b.x), f2b(b.y), f2b(b.z), f2b(b.w)};
    *(uint4*)(out + i) = *(const uint4*)v;
}

// ---------------------------------------------------------------------------
// Weight transpose+convert: W fp32 [k][n] (2048x2048) -> Wt bf16 [n][k].
// grid (32,32), 64x64 tiles.
// ---------------------------------------------------------------------------
__global__ __launch_bounds__(256) void tr_wf(const float* __restrict__ in,
                                             uint16_t* __restrict__ out) {
    __shared__ float t[64 * 69];  // stride 69: 2-way max bank aliasing (free)
    const int tid = threadIdx.x;
    const int r0 = blockIdx.y * 64, c0 = blockIdx.x * 64;
    const int rr = tid >> 2, c16 = (tid & 3) << 4;
#pragma unroll
    for (int j = 0; j < 4; j++)
        *(float4*)&t[rr * 69 + c16 + j * 4] =
            *(const float4*)(in + (size_t)(r0 + rr) * DMODEL + c0 + c16 + j * 4);
    __syncthreads();
    const int oc = tid >> 2, r16 = (tid & 3) << 4;
    uint16_t v[16] __attribute__((aligned(16)));
#pragma unroll
    for (int j = 0; j < 16; j++) v[j] = f2b(t[(r16 + j) * 69 + oc]);
    uint16_t* o = out + (size_t)(c0 + oc) * DMODEL + r0 + r16;
    *(uint4*)o = *(const uint4*)v;
    *(uint4*)(o + 8) = *(const uint4*)(v + 8);
}

// ---------------------------------------------------------------------------
// 256x256 GEMM, BK=64, 8 waves, per-phase schedule w/ counted vmcnt.
// (unchanged from Round 8 — measured best: ~110 us/dispatch)
// ---------------------------------------------------------------------------
__global__ __launch_bounds__(512, 2) void gemm256(const uint16_t* __restrict__ A,
                                                  const uint16_t* __restrict__ Bt,
                                                  const float* __restrict__ bias,
                                                  void* __restrict__ Cout,
                                                  float scale, int mode, int tld) {
    __shared__ __attribute__((aligned(16))) uint16_t As[2][32 * 512];  // 2x32KiB
    __shared__ __attribute__((aligned(16))) uint16_t Bs[2][32 * 512];  // 2x32KiB

    const int tid = threadIdx.x, lane = tid & 63, w = tid >> 6;  // 8 waves
    const int wr = w >> 2, wc = w & 3;       // wave grid 2(M) x 4(N)
    const int col = lane & 15, quad = lane >> 4;

    const int nwg = gridDim.x, cpx = nwg >> 3;
    const int swz = ((int)blockIdx.x & 7) * cpx + ((int)blockIdx.x >> 3);
    const long m0 = (long)(swz >> 3) * 256;
    const long n0 = (long)(swz & 7) * 256;

    const uint16_t* Ab = A + (m0 + col) * (size_t)DMODEL + quad * 8;
    const uint16_t* Bb = Bt + (n0 + col) * (size_t)DMODEL + quad * 8;
    const int g0 = w * 2, g1 = w * 2 + 1;

#define STG_A(bf, kt, kk)                                                      \
    do {                                                                       \
        GLD16(Ab + (size_t)(g0 * 16) * DMODEL + (kt) * 64 + (kk) * 32,         \
              &As[bf][(g0 * 2 + (kk)) * 512]);                                 \
        GLD16(Ab + (size_t)(g1 * 16) * DMODEL + (kt) * 64 + (kk) * 32,         \
              &As[bf][(g1 * 2 + (kk)) * 512]);                                 \
    } while (0)
#define STG_B(bf, kt, kk)                                                      \
    do {                                                                       \
        GLD16(Bb + (size_t)(g0 * 16) * DMODEL + (kt) * 64 + (kk) * 32,         \
              &Bs[bf][(g0 * 2 + (kk)) * 512]);                                 \
        GLD16(Bb + (size_t)(g1 * 16) * DMODEL + (kt) * 64 + (kk) * 32,         \
              &Bs[bf][(g1 * 2 + (kk)) * 512]);                                 \
    } while (0)

    floatx4 acc[8][4];
#pragma unroll
    for (int m = 0; m < 8; m++)
#pragma unroll
        for (int n = 0; n < 4; n++) acc[m][n] = (floatx4){0.f, 0.f, 0.f, 0.f};

    const int NT = DMODEL / 64;  // 32 K-tiles
    STG_A(0, 0, 0); STG_B(0, 0, 0);
    STG_A(0, 0, 1); STG_B(0, 0, 1);
    STG_A(1, 1, 0); STG_B(1, 1, 0);    // 12 loads in flight
    WAITVMC(8);                        // retire A0(0),B0(0)
    __builtin_amdgcn_s_barrier();

    bf16x8 afr[4], bfr[4];

#define PHASE(MS, KK, READB, STAGE_STMT, TAILW)                                \
    do {                                                                       \
        if (READB) {                                                           \
            _Pragma("unroll") for (int n = 0; n < 4; n++)                      \
                bfr[n] = *(const bf16x8*)&Bs[cur][((wc * 4 + n) * 2 + (KK)) *  \
                                                     512 + lane * 8];          \
        }                                                                      \
        _Pragma("unroll") for (int m = 0; m < 4; m++)                          \
            afr[m] = *(const bf16x8*)&As[cur][((wr * 8 + (MS)*4 + m) * 2 +     \
                                               (KK)) * 512 + lane * 8];        \
        STAGE_STMT;                                                            \
        __builtin_amdgcn_s_barrier();                                          \
        WAITLGKM0;                                                             \
        __builtin_amdgcn_s_setprio(1);                                         \
        _Pragma("unroll") for (int m = 0; m < 4; m++)                          \
            _Pragma("unroll") for (int n = 0; n < 4; n++)                      \
                acc[(MS)*4 + m][n] = __builtin_amdgcn_mfma_f32_16x16x32_bf16(  \
                    afr[m], bfr[n], acc[(MS)*4 + m][n], 0, 0, 0);              \
        __builtin_amdgcn_s_setprio(0);                                         \
        TAILW;                                                                 \
        __builtin_amdgcn_s_barrier();                                          \
    } while (0)

#pragma unroll 1
    for (int t = 0; t < NT; ++t) {
        const int cur = t & 1, nxt = cur ^ 1;
        PHASE(0, 0, 1, { if (t + 1 < NT) STG_A(nxt, t + 1, 1); }, {});
        PHASE(1, 0, 0, { if (t + 1 < NT) STG_B(nxt, t + 1, 1); },
              { if (t == NT - 1) { WAITVMC(0); } else { WAITVMC(8); } });
        PHASE(0, 1, 1, { if (t + 2 < NT) STG_A(cur, t + 2, 0); }, {});
        PHASE(1, 1, 0, { if (t + 2 < NT) STG_B(cur, t + 2, 0); },
              { if (t == NT - 2) { WAITVMC(2); }
                else if (t < NT - 2) { WAITVMC(8); } });
    }
#undef PHASE
#undef STG_A
#undef STG_B

    float bv[4];
#pragma unroll
    for (int n = 0; n < 4; n++) bv[n] = bias[n0 + wc * 64 + n * 16 + col];
#pragma unroll
    for (int m = 0; m < 8; m++) {
        const long row = m0 + wr * 128 + m * 16 + quad * 4;
#pragma unroll
        for (int n = 0; n < 4; n++) {
            const long cc = n0 + wc * 64 + n * 16 + col;
            if (mode == 2) {
                uint16_t tmp[4] __attribute__((aligned(8)));
#pragma unroll
                for (int r = 0; r < 4; r++)
                    tmp[r] = f2b((acc[m][n][r] + bv[n]) * scale);
                *(uint2*)&((uint16_t*)Cout)[(size_t)cc * tld + row] =
                    *(const uint2*)tmp;
            } else {
#pragma unroll
                for (int r = 0; r < 4; r++) {
                    const float v = (acc[m][n][r] + bv[n]) * scale;
                    const long idx = (row + r) * DMODEL + cc;
                    if (mode == 1) ((float*)Cout)[idx] = v;
                    else           ((uint16_t*)Cout)[idx] = f2b(v);
                }
            }
        }
    }
}

// ---------------------------------------------------------------------------
// 128-tile GEMM (m97 structure) — per-batch fallback paths.
// ---------------------------------------------------------------------------
__global__ __launch_bounds__(256, 2) void gemm(const uint16_t* __restrict__ A,
                                               const uint16_t* __restrict__ Bt,
                                               const float* __restrict__ bias,
                                               void* __restrict__ Cout,
                                               float scale, int mode, int tld) {
    __shared__ __attribute__((aligned(16))) uint16_t As[128 * 32];
    __shared__ __attribute__((aligned(16))) uint16_t Bs[128 * 32];
    const int tid = threadIdx.x, lane = tid & 63, w = tid >> 6;
    const int wr = w >> 1, wc = w & 1;
    const int col = lane & 15, quad = lane >> 4;
    const long m0 = (long)blockIdx.y * 128, n0 = (long)blockIdx.x * 128;

    floatx4 acc[4][4];
#pragma unroll
    for (int i = 0; i < 4; i++)
#pragma unroll
        for (int j = 0; j < 4; j++) acc[i][j] = (floatx4){0.f, 0.f, 0.f, 0.f};

    const int srow = tid >> 2, sc = (tid & 3) << 3;
    const uint16_t* Ag0 = A + (m0 + srow) * DMODEL + sc;
    const uint16_t* Bg0 = Bt + (n0 + srow) * DMODEL + sc;
    const long rstep = (long)64 * DMODEL;
    uint16_t* AsW = &As[w * 512];
    uint16_t* BsW = &Bs[w * 512];

    for (int kt = 0; kt < DMODEL; kt += 32) {
        GLD16(Ag0 + kt, AsW);
        GLD16(Ag0 + rstep + kt, AsW + 2048);
        GLD16(Bg0 + kt, BsW);
        GLD16(Bg0 + rstep + kt, BsW + 2048);
        __syncthreads();
        bf16x8 af[4], bfr[4];
#pragma unroll
        for (int i = 0; i < 4; i++)
            af[i] = *(const bf16x8*)&As[(wr * 64 + i * 16 + col) * 32 + quad * 8];
#pragma unroll
        for (int j = 0; j < 4; j++)
            bfr[j] = *(const bf16x8*)&Bs[(wc * 64 + j * 16 + col) * 32 + quad * 8];
#pragma unroll
        for (int i = 0; i < 4; i++)
#pragma unroll
            for (int j = 0; j < 4; j++)
                acc[i][j] = __builtin_amdgcn_mfma_f32_16x16x32_bf16(af[i], bfr[j],
                                                                    acc[i][j], 0, 0, 0);
        __syncthreads();
    }

    float bv[4];
#pragma unroll
    for (int j = 0; j < 4; j++) bv[j] = bias[n0 + wc * 64 + j * 16 + col];
#pragma unroll
    for (int i = 0; i < 4; i++) {
        const long row = m0 + wr * 64 + i * 16 + quad * 4;
#pragma unroll
        for (int j = 0; j < 4; j++) {
            const long cc = n0 + wc * 64 + j * 16 + col;
            if (mode == 2) {
                uint16_t tmp[4] __attribute__((aligned(8)));
#pragma unroll
                for (int r = 0; r < 4; r++)
                    tmp[r] = f2b((acc[i][j][r] + bv[j]) * scale);
                *(uint2*)&((uint16_t*)Cout)[(size_t)cc * tld + row] =
                    *(const uint2*)tmp;
            } else {
#pragma unroll
                for (int r = 0; r < 4; r++) {
                    const float v = (acc[i][j][r] + bv[j]) * scale;
                    const long idx = (row + r) * DMODEL + cc;
                    if (mode == 1) ((float*)Cout)[idx] = v;
                    else           ((uint16_t*)Cout)[idx] = f2b(v);
                }
            }
        }
    }
}

// ---------------------------------------------------------------------------
// Flash attention, causal, in-place (O overwrites Q). NEW this round:
// SWAPPED QK^T (mfma(K,Q) -> C[key][q], q lane-local) + IN-REGISTER P repack
// (cvt_pk_bf16 + shfl_xor(16)/shfl_xor(32) butterfly) -> Ps LDS buffer
// DELETED. LDS = Ks+Vs = 32 KiB only; K/V staged via global_load_lds into
// fragment-linear blocks (conflict-free; permutation in per-lane global src).
// Occupancy rises 8 -> ~12 waves/CU (launch_bounds(256,3), VGPR<=170).
// Grid (16, nbatch*16): qi = 15-bx -> largest blocks dispatch first (LPT).
// ---------------------------------------------------------------------------
__global__ __launch_bounds__(256, 3) void flash(uint16_t* __restrict__ QO,
                                                const uint16_t* __restrict__ Kp,
                                                const uint16_t* __restrict__ Vt,
                                                int vld) {
    // fragment-linear: block = MFMA fragment, slot = lane.
    // Ks block (jk*4+kk) lane l = K[key0+jk*16+(l&15)][kk*32+(l>>4)*8 ..+8]
    // Vs block (jd*2+k2) lane l = V^T[d=jd*16+(l&15)][key0+k2*32+(l>>4)*8 ..+8]
    __shared__ __attribute__((aligned(16))) uint16_t Ks[16 * 512];
    __shared__ __attribute__((aligned(16))) uint16_t Vs[16 * 512];

    const int tid = threadIdx.x, lane = tid & 63, w = tid >> 6;
    const int col = lane & 15, quad = lane >> 4;
    const int h = blockIdx.y & 15, b = blockIdx.y >> 4;
    const size_t brow = (size_t)b * SEQ;
    const int qi = 15 - (int)blockIdx.x;   // LPT: big blocks first
    const int q0 = qi * 128;

    const uint16_t* kbase = Kp + brow * DMODEL + h * HD;
    const uint16_t* vtbase = Vt + (size_t)(h * HD) * vld + brow;
    uint16_t* qbase = QO + (brow + q0 + w * 32) * DMODEL + h * HD;

    // per-lane GLD sources (wave w stages K rows w*16.., V d-rows w*32..)
    const uint16_t* kg = kbase + (size_t)(w * 16 + col) * DMODEL + quad * 8;
    const uint16_t* vg0 = vtbase + (size_t)(w * 32 + col) * vld + quad * 8;
    const uint16_t* vg1 = vtbase + (size_t)(w * 32 + 16 + col) * vld + quad * 8;

    bf16x8 qf[2][4];
#pragma unroll
    for (int i = 0; i < 2; i++)
#pragma unroll
        for (int kk = 0; kk < 4; kk++)
            qf[i][kk] = *(const bf16x8*)(qbase + (size_t)(i * 16 + col) * DMODEL +
                                         kk * 32 + quad * 8);

    floatx4 accO[2][8];
#pragma unroll
    for (int i = 0; i < 2; i++)
#pragma unroll
        for (int jd = 0; jd < 8; jd++) accO[i][jd] = (floatx4){0.f, 0.f, 0.f, 0.f};
    float mrun[2] = {-1e30f, -1e30f}, lrun[2] = {0.f, 0.f};

    const int nkt = 2 * qi + 2;
    for (int ki = 0; ki < nkt; ki++) {
        const size_t key0 = (size_t)ki * 64;
        // ---- stage K/V tile (async, linear dest, conflict-free) ----
#pragma unroll
        for (int p = 0; p < 4; p++)
            GLD16(kg + key0 * DMODEL + p * 32, &Ks[(w * 4 + p) * 512]);
#pragma unroll
        for (int k2 = 0; k2 < 2; k2++) {
            GLD16(vg0 + key0 + k2 * 32, &Vs[((w * 2 + 0) * 2 + k2) * 512]);
            GLD16(vg1 + key0 + k2 * 32, &Vs[((w * 2 + 1) * 2 + k2) * 512]);
        }
        __syncthreads();  // drains vmcnt(0): tile ready

        // ---- QK^T, SWAPPED: C[key][q]; lane holds q=col, keys quad*4+r ----
        floatx4 s[2][4];
#pragma unroll
        for (int i = 0; i < 2; i++)
#pragma unroll
            for (int jk = 0; jk < 4; jk++) s[i][jk] = (floatx4){0.f, 0.f, 0.f, 0.f};
        __builtin_amdgcn_s_setprio(1);
#pragma unroll
        for (int jk = 0; jk < 4; jk++)
#pragma unroll
            for (int kk = 0; kk < 4; kk++) {
                const bf16x8 bb = *(const bf16x8*)&Ks[(jk * 4 + kk) * 512 + lane * 8];
#pragma unroll
                for (int i = 0; i < 2; i++)
                    s[i][jk] = __builtin_amdgcn_mfma_f32_16x16x32_bf16(bb, qf[i][kk],
                                                                       s[i][jk], 0, 0, 0);
            }
        __builtin_amdgcn_s_setprio(0);

        // ---- causal mask: key = key0+jk*16+quad*4+r, q = q0+w*32+i*16+col --
        if ((int)key0 + 63 > q0 + w * 32) {
#pragma unroll
            for (int i = 0; i < 2; i++) {
                const int qg = q0 + w * 32 + i * 16 + col;
#pragma unroll
                for (int jk = 0; jk < 4; jk++)
#pragma unroll
                    for (int r = 0; r < 4; r++) {
                        const int key = (int)key0 + jk * 16 + quad * 4 + r;
                        if (key > qg) s[i][jk][r] = -1e30f;
                    }
            }
        }

        // ---- online softmax: q lane-local; rows split over 4 quad-lanes ----
        float abr[2][4];
#pragma unroll
        for (int i = 0; i < 2; i++) {
            float mx = s[i][0][0];
#pragma unroll
            for (int jk = 0; jk < 4; jk++)
#pragma unroll
                for (int r = 0; r < 4; r++) mx = fmaxf(mx, s[i][jk][r]);
            mx = fmaxf(mx, __shfl_xor(mx, 16, 64));
            mx = fmaxf(mx, __shfl_xor(mx, 32, 64));
            mx = fmaxf(mx, mrun[i]);
            const float al = exp2f((mrun[i] - mx) * LOG2E);
            mrun[i] = mx;
            float ps = 0.f;
#pragma unroll
            for (int jk = 0; jk < 4; jk++)
#pragma unroll
                for (int r = 0; r < 4; r++) {
                    const float p = exp2f((s[i][jk][r] - mx) * LOG2E);
                    s[i][jk][r] = p;
                    ps += p;
                }
            lrun[i] = lrun[i] * al + ps;  // partial (this lane's keys)
#pragma unroll
            for (int r = 0; r < 4; r++) abr[i][r] = __shfl(al, quad * 4 + r, 64);
        }
#pragma unroll
        for (int i = 0; i < 2; i++)
#pragma unroll
            for (int jd = 0; jd < 8; jd++)
#pragma unroll
                for (int r = 0; r < 4; r++) accO[i][jd][r] *= abr[i][r];

        // ---- in-register P repack: C-layout -> A-operand (rows=q, k=key) ---
        // target quad needs keys k2*32 + quad*8..+7: pair-exchange (xor16)
        // then cross-pair (xor32); quads 0,3 keep own, 1,2 take received.
        bf16x8 pa[2][2];
#pragma unroll
        for (int i = 0; i < 2; i++)
#pragma unroll
            for (int k2 = 0; k2 < 2; k2++) {
                const int jlo = 2 * k2, jhi = jlo + 1;
                const uint32_t c0l = cvtpk(s[i][jlo][0], s[i][jlo][1]);
                const uint32_t c1l = cvtpk(s[i][jlo][2], s[i][jlo][3]);
                const uint32_t c0h = cvtpk(s[i][jhi][0], s[i][jhi][1]);
                const uint32_t c1h = cvtpk(s[i][jhi][2], s[i][jhi][3]);
                const uint32_t n0l = __shfl_xor(c0l, 16, 64);
                const uint32_t n1l = __shfl_xor(c1l, 16, 64);
                const uint32_t n0h = __shfl_xor(c0h, 16, 64);
                const uint32_t n1h = __shfl_xor(c1h, 16, 64);
                const bool oddq = (quad & 1) != 0;
                uint4 blo = oddq ? make_uint4(n0l, n1l, c0l, c1l)
                                 : make_uint4(c0l, c1l, n0l, n1l);
                uint4 bhi = oddq ? make_uint4(n0h, n1h, c0h, c1h)
                                 : make_uint4(c0h, c1h, n0h, n1h);
                uint4 snd = (quad < 2) ? bhi : blo;
                uint4 rcv;
                rcv.x = __shfl_xor(snd.x, 32, 64);
                rcv.y = __shfl_xor(snd.y, 32, 64);
                rcv.z = __shfl_xor(snd.z, 32, 64);
                rcv.w = __shfl_xor(snd.w, 32, 64);
                uint4 kee = (quad >= 2) ? bhi : blo;
                uint4 sel = (quad == 1 || quad == 2) ? rcv : kee;
                union { uint4 u; bf16x8 v; } cv;
                cv.u = sel;
                pa[i][k2] = cv.v;
            }

        // ---- PV ----
        __builtin_amdgcn_s_setprio(1);
#pragma unroll
        for (int jd = 0; jd < 8; jd++)
#pragma unroll
            for (int k2 = 0; k2 < 2; k2++) {
                const bf16x8 vvv = *(const bf16x8*)&Vs[(jd * 2 + k2) * 512 + lane * 8];
#pragma unroll
                for (int i = 0; i < 2; i++)
                    accO[i][jd] = __builtin_amdgcn_mfma_f32_16x16x32_bf16(pa[i][k2], vvv,
                                                                          accO[i][jd], 0, 0, 0);
            }
        __builtin_amdgcn_s_setprio(0);
        __syncthreads();  // all LDS reads done before next tile's GLD
    }

    // ---- epilogue: finish l, broadcast to accO row-layout, write O ----
    float ibr[2][4];
#pragma unroll
    for (int i = 0; i < 2; i++) {
        float l = lrun[i];
        l += __shfl_xor(l, 16, 64);
        l += __shfl_xor(l, 32, 64);
        const float iv = 1.0f / l;
#pragma unroll
        for (int r = 0; r < 4; r++) ibr[i][r] = __shfl(iv, quad * 4 + r, 64);
    }
#pragma unroll
    for (int i = 0; i < 2; i++)
#pragma unroll
        for (int jd = 0; jd < 8; jd++)
#pragma unroll
            for (int r = 0; r < 4; r++)
                qbase[(size_t)(i * 16 + quad * 4 + r) * DMODEL + jd * 16 + col] =
                    f2b(accO[i][jd][r] * ibr[i][r]);
}

// ---------------------------------------------------------------------------
extern "C" void kernel_launch(void* const* d_in, const int* in_sizes, int n_in,
                              void* d_out, int out_size, void* d_ws, size_t ws_size,
                              hipStream_t stream) {
    const float* X   = (const float*)d_in[0];
    float*       msk = (float*)d_in[1];  // scratch in tiny-ws fallback
    const float* wq  = (const float*)d_in[2];
    const float* wqb = (const float*)d_in[3];
    const float* wk  = (const float*)d_in[4];
    const float* wkb = (const float*)d_in[5];
    const float* wv  = (const float*)d_in[6];
    const float* wvb = (const float*)d_in[7];
    const float* wo  = (const float*)d_in[8];
    const float* wob = (const float*)d_in[9];
    float* out = (float*)d_out;

    char* ws = (char*)d_ws;
    const size_t MB = 1ull << 20;
    dim3 tb(256), tb512(512), gT(32, 32);
    const float qs = 0.08838834764831845f;  // 1/sqrt(128)

    if (ws_size >= 136 * MB) {
        // ---- whole-problem path ----
        uint16_t* Xb = (uint16_t*)(ws);
        uint16_t* Qb = (uint16_t*)(ws + 32 * MB);
        uint16_t* Kb = (uint16_t*)(ws + 64 * MB);
        uint16_t* Vb = (uint16_t*)(ws + 96 * MB);  // holds Vt [2048][8192]
        uint16_t* Wt = (uint16_t*)(ws + 128 * MB);
        dim3 g256((MTOT / 256) * (DMODEL / 256));  // 256 blocks, 1/CU
        dim3 gF(16, 64);
        cvt_bf16<<<8192, tb, 0, stream>>>(X, Xb, MTOT * DMODEL);
        tr_wf<<<gT, tb, 0, stream>>>(wq, Wt);
        gemm256<<<g256, tb512, 0, stream>>>(Xb, Wt, wqb, Qb, qs, 0, 0);
        tr_wf<<<gT, tb, 0, stream>>>(wk, Wt);
        gemm256<<<g256, tb512, 0, stream>>>(Xb, Wt, wkb, Kb, 1.0f, 0, 0);
        tr_wf<<<gT, tb, 0, stream>>>(wv, Wt);
        gemm256<<<g256, tb512, 0, stream>>>(Xb, Wt, wvb, Vb, 1.0f, 2, MTOT);
        flash<<<gF, tb, 0, stream>>>(Qb, Kb, Vb, MTOT);  // ctx in-place over Q
        tr_wf<<<gT, tb, 0, stream>>>(wo, Wt);
        gemm256<<<g256, tb512, 0, stream>>>(Qb, Wt, wob, out, 1.0f, 1, 0);
    } else {
        // ---- per-batch paths (128-tile gemm kept here) ----
        uint16_t* Xb = (uint16_t*)(ws);
        uint16_t* Qb = (uint16_t*)(ws + 8 * MB);
        uint16_t *Kb, *Vb, *Wt;
        if (ws_size >= 40 * MB) {
            Kb = (uint16_t*)(ws + 16 * MB);
            Vb = (uint16_t*)(ws + 24 * MB);
            Wt = (uint16_t*)(ws + 32 * MB);
        } else {
            Kb = (uint16_t*)msk;
            Vb = Kb + (size_t)SEQ * DMODEL;
            Wt = (uint16_t*)(ws + 16 * MB);
        }
        dim3 gG(16, 16), gF(16, 16);
        for (int b = 0; b < BATCH; b++) {
            const float* Xf = X + (size_t)b * SEQ * DMODEL;
            float* Ob = out + (size_t)b * SEQ * DMODEL;
            cvt_bf16<<<2048, tb, 0, stream>>>(Xf, Xb, SEQ * DMODEL);
            tr_wf<<<gT, tb, 0, stream>>>(wq, Wt);
            gemm<<<gG, tb, 0, stream>>>(Xb, Wt, wqb, Qb, qs, 0, 0);
            tr_wf<<<gT, tb, 0, stream>>>(wk, Wt);
            gemm<<<gG, tb, 0, stream>>>(Xb, Wt, wkb, Kb, 1.0f, 0, 0);
            tr_wf<<<gT, tb, 0, stream>>>(wv, Wt);
            gemm<<<gG, tb, 0, stream>>>(Xb, Wt, wvb, Vb, 1.0f, 2, SEQ);
            flash<<<gF, tb, 0, stream>>>(Qb, Kb, Vb, SEQ);
            tr_wf<<<gT, tb, 0, stream>>>(wo, Wt);
            gemm<<<gG, tb, 0, stream>>>(Qb, Wt, wob, Ob, 1.0f, 1, 0);
        }
    }

    (void)in_sizes; (void)n_in; (void)out_size;
}

// Round 12
// 819.402 us; speedup vs baseline: 1.0973x; 1.0973x over previous
//
#include <hip/hip_runtime.h>
#include <stdint.h>

#define DMODEL 2048
#define NH 16
#define HD 128
#define BATCH 4
#define SEQ 2048
#define MTOT (BATCH * SEQ)  // 8192
#define LOG2E 1.44269504088896340736f

typedef __bf16 bf16x8 __attribute__((ext_vector_type(8)));
typedef float floatx4 __attribute__((ext_vector_type(4)));

__device__ __forceinline__ uint16_t f2b(float f) {
    union { float f; uint32_t i; } v; v.f = f;
    uint32_t r = v.i + 0x7fffu + ((v.i >> 16) & 1u);
    return (uint16_t)(r >> 16);
}

// pack two f32 -> one u32 of 2 bf16 (RNE). No builtin on gfx950 (m240).
__device__ __forceinline__ uint32_t cvtpk(float lo, float hi) {
    uint32_t r;
    asm("v_cvt_pk_bf16_f32 %0, %1, %2" : "=v"(r) : "v"(lo), "v"(hi));
    return r;
}

// async global->LDS, 16B per lane, wave-uniform LDS base + lane*16
#define GLD16(gp, lp)                                                          \
    __builtin_amdgcn_global_load_lds(                                          \
        (__attribute__((address_space(1))) unsigned int*)(gp),                 \
        (__attribute__((address_space(3))) unsigned int*)(lp), 16, 0, 0)

#define WAITVMC(N) asm volatile("s_waitcnt vmcnt(" #N ")" ::: "memory")
#define WAITLGKM0                                                              \
    do {                                                                       \
        asm volatile("s_waitcnt lgkmcnt(0)" ::: "memory");                     \
        __builtin_amdgcn_sched_barrier(0);                                     \
    } while (0)

// ---------------------------------------------------------------------------
// fp32 -> bf16 elementwise convert. n multiple of 8. grid n/2048.
// ---------------------------------------------------------------------------
__global__ __launch_bounds__(256) void cvt_bf16(const float* __restrict__ in,
                                                uint16_t* __restrict__ out, int n) {
    const int i = (blockIdx.x * 256 + threadIdx.x) * 8;
    if (i >= n) return;
    const float4 a = *(const float4*)(in + i);
    const float4 b = *(const float4*)(in + i + 4);
    uint16_t v[8] __attribute__((aligned(16))) = {
        f2b(a.x), f2b(a.y), f2b(a.z), f2b(a.w),
        f2b(b.x), f2b(b.y), f2b(b.z), f2b(b.w)};
    *(uint4*)(out + i) = *(const uint4*)v;
}

// ---------------------------------------------------------------------------
// Weight transpose+convert: W fp32 [k][n] (2048x2048) -> Wt bf16 [n][k].
// grid (32,32), 64x64 tiles.
// ---------------------------------------------------------------------------
__global__ __launch_bounds__(256) void tr_wf(const float* __restrict__ in,
                                             uint16_t* __restrict__ out) {
    __shared__ float t[64 * 69];  // stride 69: 2-way max bank aliasing (free)
    const int tid = threadIdx.x;
    const int r0 = blockIdx.y * 64, c0 = blockIdx.x * 64;
    const int rr = tid >> 2, c16 = (tid & 3) << 4;
#pragma unroll
    for (int j = 0; j < 4; j++)
        *(float4*)&t[rr * 69 + c16 + j * 4] =
            *(const float4*)(in + (size_t)(r0 + rr) * DMODEL + c0 + c16 + j * 4);
    __syncthreads();
    const int oc = tid >> 2, r16 = (tid & 3) << 4;
    uint16_t v[16] __attribute__((aligned(16)));
#pragma unroll
    for (int j = 0; j < 16; j++) v[j] = f2b(t[(r16 + j) * 69 + oc]);
    uint16_t* o = out + (size_t)(c0 + oc) * DMODEL + r0 + r16;
    *(uint4*)o = *(const uint4*)v;
    *(uint4*)(o + 8) = *(const uint4*)(v + 8);
}

// ---------------------------------------------------------------------------
// 256x256 GEMM, BK=64, 8 waves, per-phase schedule w/ counted vmcnt.
// (unchanged — measured ~110 us/dispatch)
// ---------------------------------------------------------------------------
__global__ __launch_bounds__(512, 2) void gemm256(const uint16_t* __restrict__ A,
                                                  const uint16_t* __restrict__ Bt,
                                                  const float* __restrict__ bias,
                                                  void* __restrict__ Cout,
                                                  float scale, int mode, int tld) {
    __shared__ __attribute__((aligned(16))) uint16_t As[2][32 * 512];  // 2x32KiB
    __shared__ __attribute__((aligned(16))) uint16_t Bs[2][32 * 512];  // 2x32KiB

    const int tid = threadIdx.x, lane = tid & 63, w = tid >> 6;  // 8 waves
    const int wr = w >> 2, wc = w & 3;       // wave grid 2(M) x 4(N)
    const int col = lane & 15, quad = lane >> 4;

    const int nwg = gridDim.x, cpx = nwg >> 3;
    const int swz = ((int)blockIdx.x & 7) * cpx + ((int)blockIdx.x >> 3);
    const long m0 = (long)(swz >> 3) * 256;
    const long n0 = (long)(swz & 7) * 256;

    const uint16_t* Ab = A + (m0 + col) * (size_t)DMODEL + quad * 8;
    const uint16_t* Bb = Bt + (n0 + col) * (size_t)DMODEL + quad * 8;
    const int g0 = w * 2, g1 = w * 2 + 1;

#define STG_A(bf, kt, kk)                                                      \
    do {                                                                       \
        GLD16(Ab + (size_t)(g0 * 16) * DMODEL + (kt) * 64 + (kk) * 32,         \
              &As[bf][(g0 * 2 + (kk)) * 512]);                                 \
        GLD16(Ab + (size_t)(g1 * 16) * DMODEL + (kt) * 64 + (kk) * 32,         \
              &As[bf][(g1 * 2 + (kk)) * 512]);                                 \
    } while (0)
#define STG_B(bf, kt, kk)                                                      \
    do {                                                                       \
        GLD16(Bb + (size_t)(g0 * 16) * DMODEL + (kt) * 64 + (kk) * 32,         \
              &Bs[bf][(g0 * 2 + (kk)) * 512]);                                 \
        GLD16(Bb + (size_t)(g1 * 16) * DMODEL + (kt) * 64 + (kk) * 32,         \
              &Bs[bf][(g1 * 2 + (kk)) * 512]);                                 \
    } while (0)

    floatx4 acc[8][4];
#pragma unroll
    for (int m = 0; m < 8; m++)
#pragma unroll
        for (int n = 0; n < 4; n++) acc[m][n] = (floatx4){0.f, 0.f, 0.f, 0.f};

    const int NT = DMODEL / 64;  // 32 K-tiles
    STG_A(0, 0, 0); STG_B(0, 0, 0);
    STG_A(0, 0, 1); STG_B(0, 0, 1);
    STG_A(1, 1, 0); STG_B(1, 1, 0);    // 12 loads in flight
    WAITVMC(8);                        // retire A0(0),B0(0)
    __builtin_amdgcn_s_barrier();

    bf16x8 afr[4], bfr[4];

#define PHASE(MS, KK, READB, STAGE_STMT, TAILW)                                \
    do {                                                                       \
        if (READB) {                                                           \
            _Pragma("unroll") for (int n = 0; n < 4; n++)                      \
                bfr[n] = *(const bf16x8*)&Bs[cur][((wc * 4 + n) * 2 + (KK)) *  \
                                                     512 + lane * 8];          \
        }                                                                      \
        _Pragma("unroll") for (int m = 0; m < 4; m++)                          \
            afr[m] = *(const bf16x8*)&As[cur][((wr * 8 + (MS)*4 + m) * 2 +     \
                                               (KK)) * 512 + lane * 8];        \
        STAGE_STMT;                                                            \
        __builtin_amdgcn_s_barrier();                                          \
        WAITLGKM0;                                                             \
        __builtin_amdgcn_s_setprio(1);                                         \
        _Pragma("unroll") for (int m = 0; m < 4; m++)                          \
            _Pragma("unroll") for (int n = 0; n < 4; n++)                      \
                acc[(MS)*4 + m][n] = __builtin_amdgcn_mfma_f32_16x16x32_bf16(  \
                    afr[m], bfr[n], acc[(MS)*4 + m][n], 0, 0, 0);              \
        __builtin_amdgcn_s_setprio(0);                                         \
        TAILW;                                                                 \
        __builtin_amdgcn_s_barrier();                                          \
    } while (0)

#pragma unroll 1
    for (int t = 0; t < NT; ++t) {
        const int cur = t & 1, nxt = cur ^ 1;
        PHASE(0, 0, 1, { if (t + 1 < NT) STG_A(nxt, t + 1, 1); }, {});
        PHASE(1, 0, 0, { if (t + 1 < NT) STG_B(nxt, t + 1, 1); },
              { if (t == NT - 1) { WAITVMC(0); } else { WAITVMC(8); } });
        PHASE(0, 1, 1, { if (t + 2 < NT) STG_A(cur, t + 2, 0); }, {});
        PHASE(1, 1, 0, { if (t + 2 < NT) STG_B(cur, t + 2, 0); },
              { if (t == NT - 2) { WAITVMC(2); }
                else if (t < NT - 2) { WAITVMC(8); } });
    }
#undef PHASE
#undef STG_A
#undef STG_B

    float bv[4];
#pragma unroll
    for (int n = 0; n < 4; n++) bv[n] = bias[n0 + wc * 64 + n * 16 + col];
#pragma unroll
    for (int m = 0; m < 8; m++) {
        const long row = m0 + wr * 128 + m * 16 + quad * 4;
#pragma unroll
        for (int n = 0; n < 4; n++) {
            const long cc = n0 + wc * 64 + n * 16 + col;
            if (mode == 2) {
                uint16_t tmp[4] __attribute__((aligned(8)));
#pragma unroll
                for (int r = 0; r < 4; r++)
                    tmp[r] = f2b((acc[m][n][r] + bv[n]) * scale);
                *(uint2*)&((uint16_t*)Cout)[(size_t)cc * tld + row] =
                    *(const uint2*)tmp;
            } else {
#pragma unroll
                for (int r = 0; r < 4; r++) {
                    const float v = (acc[m][n][r] + bv[n]) * scale;
                    const long idx = (row + r) * DMODEL + cc;
                    if (mode == 1) ((float*)Cout)[idx] = v;
                    else           ((uint16_t*)Cout)[idx] = f2b(v);
                }
            }
        }
    }
}

// ---------------------------------------------------------------------------
// 128-tile GEMM (m97 structure) — per-batch fallback paths.
// ---------------------------------------------------------------------------
__global__ __launch_bounds__(256, 2) void gemm(const uint16_t* __restrict__ A,
                                               const uint16_t* __restrict__ Bt,
                                               const float* __restrict__ bias,
                                               void* __restrict__ Cout,
                                               float scale, int mode, int tld) {
    __shared__ __attribute__((aligned(16))) uint16_t As[128 * 32];
    __shared__ __attribute__((aligned(16))) uint16_t Bs[128 * 32];
    const int tid = threadIdx.x, lane = tid & 63, w = tid >> 6;
    const int wr = w >> 1, wc = w & 1;
    const int col = lane & 15, quad = lane >> 4;
    const long m0 = (long)blockIdx.y * 128, n0 = (long)blockIdx.x * 128;

    floatx4 acc[4][4];
#pragma unroll
    for (int i = 0; i < 4; i++)
#pragma unroll
        for (int j = 0; j < 4; j++) acc[i][j] = (floatx4){0.f, 0.f, 0.f, 0.f};

    const int srow = tid >> 2, sc = (tid & 3) << 3;
    const uint16_t* Ag0 = A + (m0 + srow) * DMODEL + sc;
    const uint16_t* Bg0 = Bt + (n0 + srow) * DMODEL + sc;
    const long rstep = (long)64 * DMODEL;
    uint16_t* AsW = &As[w * 512];
    uint16_t* BsW = &Bs[w * 512];

    for (int kt = 0; kt < DMODEL; kt += 32) {
        GLD16(Ag0 + kt, AsW);
        GLD16(Ag0 + rstep + kt, AsW + 2048);
        GLD16(Bg0 + kt, BsW);
        GLD16(Bg0 + rstep + kt, BsW + 2048);
        __syncthreads();
        bf16x8 af[4], bfr[4];
#pragma unroll
        for (int i = 0; i < 4; i++)
            af[i] = *(const bf16x8*)&As[(wr * 64 + i * 16 + col) * 32 + quad * 8];
#pragma unroll
        for (int j = 0; j < 4; j++)
            bfr[j] = *(const bf16x8*)&Bs[(wc * 64 + j * 16 + col) * 32 + quad * 8];
#pragma unroll
        for (int i = 0; i < 4; i++)
#pragma unroll
            for (int j = 0; j < 4; j++)
                acc[i][j] = __builtin_amdgcn_mfma_f32_16x16x32_bf16(af[i], bfr[j],
                                                                    acc[i][j], 0, 0, 0);
        __syncthreads();
    }

    float bv[4];
#pragma unroll
    for (int j = 0; j < 4; j++) bv[j] = bias[n0 + wc * 64 + j * 16 + col];
#pragma unroll
    for (int i = 0; i < 4; i++) {
        const long row = m0 + wr * 64 + i * 16 + quad * 4;
#pragma unroll
        for (int j = 0; j < 4; j++) {
            const long cc = n0 + wc * 64 + j * 16 + col;
            if (mode == 2) {
                uint16_t tmp[4] __attribute__((aligned(8)));
#pragma unroll
                for (int r = 0; r < 4; r++)
                    tmp[r] = f2b((acc[i][j][r] + bv[j]) * scale);
                *(uint2*)&((uint16_t*)Cout)[(size_t)cc * tld + row] =
                    *(const uint2*)tmp;
            } else {
#pragma unroll
                for (int r = 0; r < 4; r++) {
                    const float v = (acc[i][j][r] + bv[j]) * scale;
                    const long idx = (row + r) * DMODEL + cc;
                    if (mode == 1) ((float*)Cout)[idx] = v;
                    else           ((uint16_t*)Cout)[idx] = f2b(v);
                }
            }
        }
    }
}

// ---------------------------------------------------------------------------
// Flash attention, causal, in-place. MERGED (R8 skeleton + R9 softmax):
//  - grid (8, nbatch*16) paired halves: qi = 15-bx then bx -> exactly 34
//    K-tiles per block, 512 blocks = 2/CU, no tail (measured 20.9% occ).
//  - register-staged ONE-TILE-AHEAD prefetch: tile ki+1's global loads issue
//    right after the post-stage barrier and drain under QK^T+softmax+PV
//    (R9 removed this -> 423us regression from exposed latency; restored).
//  - swapped QK^T (mfma(K,Q) -> C[key][q], q lane-local) + in-register
//    cvt_pk/shfl repack; Ps LDS deleted (conflicts 1.1e7 -> 0, LDS 32KiB).
// V comes TRANSPOSED: Vt bf16 [2048 n][vld m]. LDS fragment-linear (block =
// MFMA fragment, slot = lane): uint4 ds_writes + b128 reads conflict-free.
// ---------------------------------------------------------------------------
__global__ __launch_bounds__(256, 2) void flash(uint16_t* __restrict__ QO,
                                                const uint16_t* __restrict__ Kp,
                                                const uint16_t* __restrict__ Vt,
                                                int vld) {
    // Ks block (jk*4+kk) lane l = K[key0+jk*16+(l&15)][kk*32+(l>>4)*8 ..+8]
    // Vs block (jd*2+k2) lane l = V^T[d=jd*16+(l&15)][key0+k2*32+(l>>4)*8 ..+8]
    __shared__ __attribute__((aligned(16))) uint16_t Ks[16 * 512];
    __shared__ __attribute__((aligned(16))) uint16_t Vs[16 * 512];

    const int tid = threadIdx.x, lane = tid & 63, w = tid >> 6;
    const int col = lane & 15, quad = lane >> 4;
    const int h = blockIdx.y & 15, b = blockIdx.y >> 4;
    const size_t brow = (size_t)b * SEQ;

    const uint16_t* kbase = Kp + brow * DMODEL + h * HD;
    const uint16_t* vtbase = Vt + (size_t)(h * HD) * vld + brow;
    // per-lane fragment-permuted staging sources (wave w: K rows w*16..,
    // V d-rows w*32..)
    const uint16_t* kg0 = kbase + (size_t)(w * 16 + col) * DMODEL + quad * 8;
    const uint16_t* vg0 = vtbase + (size_t)(w * 32 + col) * vld + quad * 8;

    for (int half = 0; half < 2; ++half) {
        const int qi = half ? (int)blockIdx.x : (15 - (int)blockIdx.x);
        const int q0 = qi * 128;
        uint16_t* qbase = QO + (brow + q0 + w * 32) * DMODEL + h * HD;

        bf16x8 qf[2][4];
#pragma unroll
        for (int i = 0; i < 2; i++)
#pragma unroll
            for (int kk = 0; kk < 4; kk++)
                qf[i][kk] = *(const bf16x8*)(qbase + (size_t)(i * 16 + col) * DMODEL +
                                             kk * 32 + quad * 8);

        floatx4 accO[2][8];
#pragma unroll
        for (int i = 0; i < 2; i++)
#pragma unroll
            for (int jd = 0; jd < 8; jd++) accO[i][jd] = (floatx4){0.f, 0.f, 0.f, 0.f};
        float mrun[2] = {-1e30f, -1e30f}, lrun[2] = {0.f, 0.f};

        const int nkt = 2 * qi + 2;

        // prologue: stage tile 0 into registers
        uint4 kv[4], vv4[4];
#pragma unroll
        for (int p = 0; p < 4; p++) kv[p] = *(const uint4*)(kg0 + p * 32);
#pragma unroll
        for (int s = 0; s < 2; s++)
#pragma unroll
            for (int k2 = 0; k2 < 2; k2++)
                vv4[s * 2 + k2] = *(const uint4*)(vg0 + (size_t)s * 16 * vld + k2 * 32);

        for (int ki = 0; ki < nkt; ki++) {
            const size_t key0 = (size_t)ki * 64;
            // ---- write staged regs to LDS (lane-linear, conflict-free) ----
#pragma unroll
            for (int p = 0; p < 4; p++)
                *(uint4*)&Ks[(w * 4 + p) * 512 + lane * 8] = kv[p];
#pragma unroll
            for (int s = 0; s < 2; s++)
#pragma unroll
                for (int k2 = 0; k2 < 2; k2++)
                    *(uint4*)&Vs[((w * 2 + s) * 2 + k2) * 512 + lane * 8] =
                        vv4[s * 2 + k2];
            __syncthreads();

            // ---- issue next tile's global loads (drain under compute) ----
            if (ki + 1 < nkt) {
                const size_t koff = key0 + 64;
#pragma unroll
                for (int p = 0; p < 4; p++)
                    kv[p] = *(const uint4*)(kg0 + koff * DMODEL + p * 32);
#pragma unroll
                for (int s = 0; s < 2; s++)
#pragma unroll
                    for (int k2 = 0; k2 < 2; k2++)
                        vv4[s * 2 + k2] = *(const uint4*)(vg0 + (size_t)s * 16 * vld +
                                                          koff + k2 * 32);
            }

            // ---- QK^T, swapped: C[key][q]; lane holds q=col, keys quad*4+r --
            floatx4 s[2][4];
#pragma unroll
            for (int i = 0; i < 2; i++)
#pragma unroll
                for (int jk = 0; jk < 4; jk++) s[i][jk] = (floatx4){0.f, 0.f, 0.f, 0.f};
            __builtin_amdgcn_s_setprio(1);
#pragma unroll
            for (int jk = 0; jk < 4; jk++)
#pragma unroll
                for (int kk = 0; kk < 4; kk++) {
                    const bf16x8 bb = *(const bf16x8*)&Ks[(jk * 4 + kk) * 512 + lane * 8];
#pragma unroll
                    for (int i = 0; i < 2; i++)
                        s[i][jk] = __builtin_amdgcn_mfma_f32_16x16x32_bf16(bb, qf[i][kk],
                                                                           s[i][jk], 0, 0, 0);
                }
            __builtin_amdgcn_s_setprio(0);

            // ---- causal mask: key = key0+jk*16+quad*4+r, q = q0+w*32+i*16+col
            if ((int)key0 + 63 > q0 + w * 32) {
#pragma unroll
                for (int i = 0; i < 2; i++) {
                    const int qg = q0 + w * 32 + i * 16 + col;
#pragma unroll
                    for (int jk = 0; jk < 4; jk++)
#pragma unroll
                        for (int r = 0; r < 4; r++) {
                            const int key = (int)key0 + jk * 16 + quad * 4 + r;
                            if (key > qg) s[i][jk][r] = -1e30f;
                        }
                }
            }

            // ---- online softmax: q lane-local; keys split over quad-lanes ---
            float abr[2][4];
#pragma unroll
            for (int i = 0; i < 2; i++) {
                float mx = s[i][0][0];
#pragma unroll
                for (int jk = 0; jk < 4; jk++)
#pragma unroll
                    for (int r = 0; r < 4; r++) mx = fmaxf(mx, s[i][jk][r]);
                mx = fmaxf(mx, __shfl_xor(mx, 16, 64));
                mx = fmaxf(mx, __shfl_xor(mx, 32, 64));
                mx = fmaxf(mx, mrun[i]);
                const float al = exp2f((mrun[i] - mx) * LOG2E);
                mrun[i] = mx;
                float ps = 0.f;
#pragma unroll
                for (int jk = 0; jk < 4; jk++)
#pragma unroll
                    for (int r = 0; r < 4; r++) {
                        const float p = exp2f((s[i][jk][r] - mx) * LOG2E);
                        s[i][jk][r] = p;
                        ps += p;
                    }
                lrun[i] = lrun[i] * al + ps;  // partial (this lane's keys)
#pragma unroll
                for (int r = 0; r < 4; r++) abr[i][r] = __shfl(al, quad * 4 + r, 64);
            }
#pragma unroll
            for (int i = 0; i < 2; i++)
#pragma unroll
                for (int jd = 0; jd < 8; jd++)
#pragma unroll
                    for (int r = 0; r < 4; r++) accO[i][jd][r] *= abr[i][r];

            // ---- in-register P repack: C-layout -> A-operand ----
            bf16x8 pa[2][2];
#pragma unroll
            for (int i = 0; i < 2; i++)
#pragma unroll
                for (int k2 = 0; k2 < 2; k2++) {
                    const int jlo = 2 * k2, jhi = jlo + 1;
                    const uint32_t c0l = cvtpk(s[i][jlo][0], s[i][jlo][1]);
                    const uint32_t c1l = cvtpk(s[i][jlo][2], s[i][jlo][3]);
                    const uint32_t c0h = cvtpk(s[i][jhi][0], s[i][jhi][1]);
                    const uint32_t c1h = cvtpk(s[i][jhi][2], s[i][jhi][3]);
                    const uint32_t n0l = __shfl_xor(c0l, 16, 64);
                    const uint32_t n1l = __shfl_xor(c1l, 16, 64);
                    const uint32_t n0h = __shfl_xor(c0h, 16, 64);
                    const uint32_t n1h = __shfl_xor(c1h, 16, 64);
                    const bool oddq = (quad & 1) != 0;
                    uint4 blo = oddq ? make_uint4(n0l, n1l, c0l, c1l)
                                     : make_uint4(c0l, c1l, n0l, n1l);
                    uint4 bhi = oddq ? make_uint4(n0h, n1h, c0h, c1h)
                                     : make_uint4(c0h, c1h, n0h, n1h);
                    uint4 snd = (quad < 2) ? bhi : blo;
                    uint4 rcv;
                    rcv.x = __shfl_xor(snd.x, 32, 64);
                    rcv.y = __shfl_xor(snd.y, 32, 64);
                    rcv.z = __shfl_xor(snd.z, 32, 64);
                    rcv.w = __shfl_xor(snd.w, 32, 64);
                    uint4 kee = (quad >= 2) ? bhi : blo;
                    uint4 sel = (quad == 1 || quad == 2) ? rcv : kee;
                    union { uint4 u; bf16x8 v; } cv;
                    cv.u = sel;
                    pa[i][k2] = cv.v;
                }

            // ---- PV ----
            __builtin_amdgcn_s_setprio(1);
#pragma unroll
            for (int jd = 0; jd < 8; jd++)
#pragma unroll
                for (int k2 = 0; k2 < 2; k2++) {
                    const bf16x8 vvv = *(const bf16x8*)&Vs[(jd * 2 + k2) * 512 + lane * 8];
#pragma unroll
                    for (int i = 0; i < 2; i++)
                        accO[i][jd] = __builtin_amdgcn_mfma_f32_16x16x32_bf16(pa[i][k2], vvv,
                                                                              accO[i][jd], 0, 0, 0);
                }
            __builtin_amdgcn_s_setprio(0);
            __syncthreads();
        }

        // ---- epilogue: finish l, broadcast, write O ----
        float ibr[2][4];
#pragma unroll
        for (int i = 0; i < 2; i++) {
            float l = lrun[i];
            l += __shfl_xor(l, 16, 64);
            l += __shfl_xor(l, 32, 64);
            const float iv = 1.0f / l;
#pragma unroll
            for (int r = 0; r < 4; r++) ibr[i][r] = __shfl(iv, quad * 4 + r, 64);
        }
#pragma unroll
        for (int i = 0; i < 2; i++)
#pragma unroll
            for (int jd = 0; jd < 8; jd++)
#pragma unroll
                for (int r = 0; r < 4; r++)
                    qbase[(size_t)(i * 16 + quad * 4 + r) * DMODEL + jd * 16 + col] =
                        f2b(accO[i][jd][r] * ibr[i][r]);
    }
}

// ---------------------------------------------------------------------------
extern "C" void kernel_launch(void* const* d_in, const int* in_sizes, int n_in,
                              void* d_out, int out_size, void* d_ws, size_t ws_size,
                              hipStream_t stream) {
    const float* X   = (const float*)d_in[0];
    float*       msk = (float*)d_in[1];  // scratch in tiny-ws fallback
    const float* wq  = (const float*)d_in[2];
    const float* wqb = (const float*)d_in[3];
    const float* wk  = (const float*)d_in[4];
    const float* wkb = (const float*)d_in[5];
    const float* wv  = (const float*)d_in[6];
    const float* wvb = (const float*)d_in[7];
    const float* wo  = (const float*)d_in[8];
    const float* wob = (const float*)d_in[9];
    float* out = (float*)d_out;

    char* ws = (char*)d_ws;
    const size_t MB = 1ull << 20;
    dim3 tb(256), tb512(512), gT(32, 32);
    const float qs = 0.08838834764831845f;  // 1/sqrt(128)

    if (ws_size >= 136 * MB) {
        // ---- whole-problem path ----
        uint16_t* Xb = (uint16_t*)(ws);
        uint16_t* Qb = (uint16_t*)(ws + 32 * MB);
        uint16_t* Kb = (uint16_t*)(ws + 64 * MB);
        uint16_t* Vb = (uint16_t*)(ws + 96 * MB);  // holds Vt [2048][8192]
        uint16_t* Wt = (uint16_t*)(ws + 128 * MB);
        dim3 g256((MTOT / 256) * (DMODEL / 256));  // 256 blocks, 1/CU
        dim3 gF(8, 64);
        cvt_bf16<<<8192, tb, 0, stream>>>(X, Xb, MTOT * DMODEL);
        tr_wf<<<gT, tb, 0, stream>>>(wq, Wt);
        gemm256<<<g256, tb512, 0, stream>>>(Xb, Wt, wqb, Qb, qs, 0, 0);
        tr_wf<<<gT, tb, 0, stream>>>(wk, Wt);
        gemm256<<<g256, tb512, 0, stream>>>(Xb, Wt, wkb, Kb, 1.0f, 0, 0);
        tr_wf<<<gT, tb, 0, stream>>>(wv, Wt);
        gemm256<<<g256, tb512, 0, stream>>>(Xb, Wt, wvb, Vb, 1.0f, 2, MTOT);
        flash<<<gF, tb, 0, stream>>>(Qb, Kb, Vb, MTOT);  // ctx in-place over Q
        tr_wf<<<gT, tb, 0, stream>>>(wo, Wt);
        gemm256<<<g256, tb512, 0, stream>>>(Qb, Wt, wob, out, 1.0f, 1, 0);
    } else {
        // ---- per-batch paths (128-tile gemm kept here) ----
        uint16_t* Xb = (uint16_t*)(ws);
        uint16_t* Qb = (uint16_t*)(ws + 8 * MB);
        uint16_t *Kb, *Vb, *Wt;
        if (ws_size >= 40 * MB) {
            Kb = (uint16_t*)(ws + 16 * MB);
            Vb = (uint16_t*)(ws + 24 * MB);
            Wt = (uint16_t*)(ws + 32 * MB);
        } else {
            Kb = (uint16_t*)msk;
            Vb = Kb + (size_t)SEQ * DMODEL;
            Wt = (uint16_t*)(ws + 16 * MB);
        }
        dim3 gG(16, 16), gF(8, 16);
        for (int b = 0; b < BATCH; b++) {
            const float* Xf = X + (size_t)b * SEQ * DMODEL;
            float* Ob = out + (size_t)b * SEQ * DMODEL;
            cvt_bf16<<<2048, tb, 0, stream>>>(Xf, Xb, SEQ * DMODEL);
            tr_wf<<<gT, tb, 0, stream>>>(wq, Wt);
            gemm<<<gG, tb, 0, stream>>>(Xb, Wt, wqb, Qb, qs, 0, 0);
            tr_wf<<<gT, tb, 0, stream>>>(wk, Wt);
            gemm<<<gG, tb, 0, stream>>>(Xb, Wt, wkb, Kb, 1.0f, 0, 0);
            tr_wf<<<gT, tb, 0, stream>>>(wv, Wt);
            gemm<<<gG, tb, 0, stream>>>(Xb, Wt, wvb, Vb, 1.0f, 2, SEQ);
            flash<<<gF, tb, 0, stream>>>(Qb, Kb, Vb, SEQ);
            tr_wf<<<gT, tb, 0, stream>>>(wo, Wt);
            gemm<<<gG, tb, 0, stream>>>(Qb, Wt, wob, Ob, 1.0f, 1, 0);
        }
    }

    (void)in_sizes; (void)n_in; (void)out_size;
}